// Round 1
// baseline (2155.978 us; speedup 1.0000x reference)
//
#include <hip/hip_runtime.h>

#define NROWS 131072
#define KCB   2048
#define DIM   256
#define MT    64    // rows per workgroup
#define CT    128   // cols per chunk
#define DS    32    // d-slice depth

typedef unsigned int u32;
typedef unsigned long long u64;

__device__ __forceinline__ u32 fkey(float f) {
    u32 b = __float_as_uint(f);
    return (b & 0x80000000u) ? ~b : (b | 0x80000000u);
}

// ---- K0: normalize embedding rows, write transposed en_t[d][k] ----
__global__ void k_prep_embed(const float* __restrict__ emb, float* __restrict__ en_t) {
    int k = blockIdx.x;         // 0..2047
    int lane = threadIdx.x;     // 0..63
    float4 v = *(const float4*)(emb + (size_t)k * DIM + 4 * lane);
    float ss = v.x * v.x + v.y * v.y + v.z * v.z + v.w * v.w;
    #pragma unroll
    for (int o = 32; o > 0; o >>= 1) ss += __shfl_down(ss, o, 64);
    ss = __shfl(ss, 0, 64);
    float n = fmaxf(sqrtf(ss), 1e-12f);
    en_t[(size_t)(4 * lane + 0) * KCB + k] = v.x / n;
    en_t[(size_t)(4 * lane + 1) * KCB + k] = v.y / n;
    en_t[(size_t)(4 * lane + 2) * KCB + k] = v.z / n;
    en_t[(size_t)(4 * lane + 3) * KCB + k] = v.w / n;
}

// ---- K1: per-row z norms ----
__global__ void k_znorm(const float* __restrict__ z, float* __restrict__ znrm) {
    int gw = (blockIdx.x * blockDim.x + threadIdx.x) >> 6;
    int lane = threadIdx.x & 63;
    int nw = (gridDim.x * blockDim.x) >> 6;
    for (int row = gw; row < NROWS; row += nw) {
        float4 v = *(const float4*)(z + (size_t)row * DIM + 4 * lane);
        float ss = v.x * v.x + v.y * v.y + v.z * v.z + v.w * v.w;
        #pragma unroll
        for (int o = 32; o > 0; o >>= 1) ss += __shfl_down(ss, o, 64);
        if (lane == 0) znrm[row] = fmaxf(sqrtf(ss), 1e-12f);
    }
}

// ---- K2: fused GEMM + row argmax (idx) + col argmax (closest, packed atomic) ----
__launch_bounds__(256, 2)
__global__ void k_main(const float* __restrict__ z, const float* __restrict__ en_t,
                       const float* __restrict__ znrm, int* __restrict__ idx_out,
                       u64* __restrict__ colmax) {
    __shared__ __align__(16) float As[DIM * MT];  // [d][row], 64 KB
    __shared__ __align__(16) float Bs[DS * CT];   // [d][col], 16 KB (reused as scratch)
    const int t = threadIdx.x;
    const int tx = t & 15, ty = t >> 4;
    const int brow = blockIdx.x * MT;

    // stage A transposed: wave reads one row (64 float4), scatters as a column
    {
        const int sub = t >> 6;      // 0..3
        const int d4  = t & 63;      // float4 index in row
        #pragma unroll
        for (int i = 0; i < 16; ++i) {
            int row = 4 * i + sub;
            float4 v = *(const float4*)(z + (size_t)(brow + row) * DIM + 4 * d4);
            As[(4 * d4 + 0) * MT + row] = v.x;
            As[(4 * d4 + 1) * MT + row] = v.y;
            As[(4 * d4 + 2) * MT + row] = v.z;
            As[(4 * d4 + 3) * MT + row] = v.w;
        }
    }
    __syncthreads();

    float rrn[4];
    #pragma unroll
    for (int i = 0; i < 4; ++i) rrn[i] = 1.0f / znrm[brow + 4 * ty + i];

    float rbV[4]; int rbC[4];
    #pragma unroll
    for (int i = 0; i < 4; ++i) { rbV[i] = -3.4e38f; rbC[i] = 0x7FFFFFFF; }

    for (int c0 = 0; c0 < KCB; c0 += CT) {
        float acc[4][8];
        #pragma unroll
        for (int i = 0; i < 4; ++i)
            #pragma unroll
            for (int j = 0; j < 8; ++j) acc[i][j] = 0.f;

        for (int s = 0; s < DIM; s += DS) {
            __syncthreads();
            #pragma unroll
            for (int j = 0; j < 4; ++j) {   // stage B slice: 32 d x 128 cols
                int l = j * 256 + t;
                int d = l >> 5;
                int c4 = l & 31;
                float4 v = *(const float4*)(en_t + (size_t)(s + d) * KCB + c0 + 4 * c4);
                *(float4*)&Bs[d * CT + 4 * c4] = v;
            }
            __syncthreads();
            #pragma unroll
            for (int dd = 0; dd < DS; ++dd) {
                const float4 a4 = *(const float4*)&As[(s + dd) * MT + 4 * ty];
                const float4 b0 = *(const float4*)&Bs[dd * CT + 4 * tx];
                const float4 b1 = *(const float4*)&Bs[dd * CT + 64 + 4 * tx];
                float a[4] = {a4.x, a4.y, a4.z, a4.w};
                float b[8] = {b0.x, b0.y, b0.z, b0.w, b1.x, b1.y, b1.z, b1.w};
                #pragma unroll
                for (int i = 0; i < 4; ++i)
                    #pragma unroll
                    for (int j = 0; j < 8; ++j)
                        acc[i][j] = fmaf(a[i], b[j], acc[i][j]);
            }
        }

        __syncthreads();                 // done with Bs as B-tile
        float2* csc = (float2*)Bs;       // scratch [16 ty][128 col]
        #pragma unroll
        for (int j = 0; j < 8; ++j) {
            int colLocal = (j < 4) ? (4 * tx + j) : (64 + 4 * tx + (j - 4));
            int colG = c0 + colLocal;
            float bv = -3.4e38f; int br = 0x7FFFFFFF;
            #pragma unroll
            for (int i = 0; i < 4; ++i) {
                float dv = acc[i][j] * rrn[i];
                int rG = brow + 4 * ty + i;
                if (dv > rbV[i] || (dv == rbV[i] && colG < rbC[i])) { rbV[i] = dv; rbC[i] = colG; }
                if (dv > bv || (dv == bv && rG < br)) { bv = dv; br = rG; }
            }
            csc[ty * CT + colLocal] = make_float2(bv, __int_as_float(br));
        }
        __syncthreads();
        if (t < CT) {
            int col = t;
            float bv = -3.4e38f; int br = 0x7FFFFFFF;
            #pragma unroll
            for (int q = 0; q < 16; ++q) {
                float2 e = csc[q * CT + col];
                float v = e.x; int r = __float_as_int(e.y);
                if (v > bv || (v == bv && r < br)) { bv = v; br = r; }
            }
            u64 packed = ((u64)fkey(bv) << 32) | (u64)(0xFFFFFFFFu - (u32)br);
            atomicMax(colmax + c0 + col, packed);
        }
    }

    // final row-argmax reduce across tx
    __syncthreads();
    float2* rsc = (float2*)Bs;           // [16 tx][64 row]
    #pragma unroll
    for (int i = 0; i < 4; ++i)
        rsc[tx * MT + 4 * ty + i] = make_float2(rbV[i], __int_as_float(rbC[i]));
    __syncthreads();
    if (t < MT) {
        int row = t;
        float bv = -3.4e38f; int bc = 0x7FFFFFFF;
        #pragma unroll
        for (int q = 0; q < 16; ++q) {
            float2 e = rsc[q * MT + row];
            float v = e.x; int c = __float_as_int(e.y);
            if (v > bv || (v == bv && c < bc)) { bv = v; bc = c; }
        }
        idx_out[brow + row] = bc;
    }
}

// ---- K3: gather z_q, write out0 (straight-through), loss partials, histogram ----
__global__ void k_gather(const float* __restrict__ z, const float* __restrict__ emb,
                         const int* __restrict__ idx, float* __restrict__ zq_out,
                         int* __restrict__ counts, float* __restrict__ partials) {
    __shared__ float red[256];
    int t = threadIdx.x;
    int lane = t & 63, w = t >> 6;
    int base = blockIdx.x * 64;
    float acc = 0.f;
    for (int r = 0; r < 16; ++r) {
        int row = base + w * 16 + r;
        int ix = idx[row];
        float4 e  = *(const float4*)(emb + (size_t)ix * DIM + 4 * lane);
        float4 zv = *(const float4*)(z + (size_t)row * DIM + 4 * lane);
        float4 o;   // z + (z_q - z), matching reference op order
        o.x = zv.x + (e.x - zv.x); o.y = zv.y + (e.y - zv.y);
        o.z = zv.z + (e.z - zv.z); o.w = zv.w + (e.w - zv.w);
        *(float4*)(zq_out + (size_t)row * DIM + 4 * lane) = o;
        float dx = e.x - zv.x, dy = e.y - zv.y, dz = e.z - zv.z, dw = e.w - zv.w;
        acc += dx * dx + dy * dy + dz * dz + dw * dw;
        if (lane == 0) atomicAdd(counts + ix, 1);
    }
    red[t] = acc;
    __syncthreads();
    #pragma unroll
    for (int o = 128; o > 0; o >>= 1) { if (t < o) red[t] += red[t + o]; __syncthreads(); }
    if (t == 0) partials[blockIdx.x] = red[0];
}

// ---- K4: final loss reduce ----
__global__ void k_loss(const float* __restrict__ partials, float* __restrict__ out_loss) {
    __shared__ float red[256];
    int t = threadIdx.x;
    float a = 0.f;
    for (int i = t; i < 2048; i += 256) a += partials[i];
    red[t] = a;
    __syncthreads();
    #pragma unroll
    for (int o = 128; o > 0; o >>= 1) { if (t < o) red[t] += red[t + o]; __syncthreads(); }
    if (t == 0) out_loss[0] = 1.25f * (red[0] / 33554432.0f);
}

// ---- K5: finalize new_embedding + new_embed_prob ----
__global__ void k_final(const float* __restrict__ z, const float* __restrict__ emb,
                        const float* __restrict__ eprob, const int* __restrict__ counts,
                        const u64* __restrict__ colmax,
                        float* __restrict__ out_emb, float* __restrict__ out_prob) {
    int k = blockIdx.x, lane = threadIdx.x;   // 2048 x 64
    u64 p = colmax[k];
    int r = (int)(0xFFFFFFFFu - (u32)(p & 0xFFFFFFFFull));
    float avg = (float)counts[k] * (1.0f / (float)NROWS);
    float nep = eprob[k] * 0.99f + avg * 0.01f;
    float reinit = expf(-(((nep * 2048.0f) * 10.0f) / 0.01f) - 0.001f);
    float4 ev = *(const float4*)(emb + (size_t)k * DIM + 4 * lane);
    float4 zv = *(const float4*)(z + (size_t)r * DIM + 4 * lane);
    float4 o;
    o.x = ev.x * (1.f - reinit) + zv.x * reinit;
    o.y = ev.y * (1.f - reinit) + zv.y * reinit;
    o.z = ev.z * (1.f - reinit) + zv.z * reinit;
    o.w = ev.w * (1.f - reinit) + zv.w * reinit;
    *(float4*)(out_emb + (size_t)k * DIM + 4 * lane) = o;
    if (lane == 0) out_prob[k] = nep;
}

extern "C" void kernel_launch(void* const* d_in, const int* in_sizes, int n_in,
                              void* d_out, int out_size, void* d_ws, size_t ws_size,
                              hipStream_t stream) {
    const float* z   = (const float*)d_in[0];
    const float* emb = (const float*)d_in[1];
    const float* epr = (const float*)d_in[2];

    float* out      = (float*)d_out;
    float* out_zq   = out;                                // NROWS*DIM
    float* out_loss = out + (size_t)NROWS * DIM;          // 1
    float* out_emb  = out_loss + 1;                       // KCB*DIM
    float* out_prob = out_emb + (size_t)KCB * DIM;        // KCB

    char* ws = (char*)d_ws;
    float* en_t   = (float*)(ws + 0);          // 2 MB
    float* znrm   = (float*)(ws + 2097152);    // 512 KB
    int*   idx    = (int*)  (ws + 2621440);    // 512 KB
    u64*   colmax = (u64*)  (ws + 3145728);    // 16 KB
    int*   counts = (int*)  (ws + 3162112);    // 8 KB
    float* parts  = (float*)(ws + 3170304);    // 8 KB

    // zero colmax + counts (contiguous 24 KB) — must reset every launch
    hipMemsetAsync(colmax, 0, 16384 + 8192, stream);

    k_prep_embed<<<KCB, 64, 0, stream>>>(emb, en_t);
    k_znorm<<<512, 256, 0, stream>>>(z, znrm);
    k_main<<<NROWS / MT, 256, 0, stream>>>(z, en_t, znrm, idx, colmax);
    k_gather<<<NROWS / 64, 256, 0, stream>>>(z, emb, idx, out_zq, counts, parts);
    k_loss<<<1, 256, 0, stream>>>(parts, out_loss);
    k_final<<<KCB, 64, 0, stream>>>(z, emb, epr, counts, colmax, out_emb, out_prob);
}

// Round 2
// 1824.045 us; speedup vs baseline: 1.1820x; 1.1820x over previous
//
#include <hip/hip_runtime.h>

#define NROWS 131072
#define KCB   2048
#define DIM   256
#define BR    128   // rows per block
#define CT    128   // cols per chunk
#define DS    32    // d-slice depth
#define LSTR  132   // padded LDS row stride (floats)
#define NCH   (KCB / CT)

typedef unsigned int u32;
typedef unsigned long long u64;

__device__ __forceinline__ u32 fkey(float f) {
    u32 b = __float_as_uint(f);
    return (b & 0x80000000u) ? ~b : (b | 0x80000000u);
}

// ---- K0: normalize embedding rows, write transposed en_t[d][k] ----
__global__ void k_prep_embed(const float* __restrict__ emb, float* __restrict__ en_t) {
    int k = blockIdx.x;         // 0..2047
    int lane = threadIdx.x;     // 0..63
    float4 v = *(const float4*)(emb + (size_t)k * DIM + 4 * lane);
    float ss = v.x * v.x + v.y * v.y + v.z * v.z + v.w * v.w;
    #pragma unroll
    for (int o = 32; o > 0; o >>= 1) ss += __shfl_down(ss, o, 64);
    ss = __shfl(ss, 0, 64);
    float n = fmaxf(sqrtf(ss), 1e-12f);
    en_t[(size_t)(4 * lane + 0) * KCB + k] = v.x / n;
    en_t[(size_t)(4 * lane + 1) * KCB + k] = v.y / n;
    en_t[(size_t)(4 * lane + 2) * KCB + k] = v.z / n;
    en_t[(size_t)(4 * lane + 3) * KCB + k] = v.w / n;
}

// ---- K1: per-row z norms ----
__global__ void k_znorm(const float* __restrict__ z, float* __restrict__ znrm) {
    int gw = (blockIdx.x * blockDim.x + threadIdx.x) >> 6;
    int lane = threadIdx.x & 63;
    int nw = (gridDim.x * blockDim.x) >> 6;
    for (int row = gw; row < NROWS; row += nw) {
        float4 v = *(const float4*)(z + (size_t)row * DIM + 4 * lane);
        float ss = v.x * v.x + v.y * v.y + v.z * v.z + v.w * v.w;
        #pragma unroll
        for (int o = 32; o > 0; o >>= 1) ss += __shfl_down(ss, o, 64);
        if (lane == 0) znrm[row] = fmaxf(sqrtf(ss), 1e-12f);
    }
}

// ---- K2: fused GEMM (8x8 micro-tile) + row argmax + col argmax ----
__launch_bounds__(256, 3)
__global__ void k_main(const float* __restrict__ z, const float* __restrict__ en_t,
                       const float* __restrict__ znrm, int* __restrict__ idx_out,
                       u64* __restrict__ colmax) {
    __shared__ __align__(16) float As[DS * LSTR];  // [d][row], 16.9 KB
    __shared__ __align__(16) float Bs[DS * LSTR];  // [d][col], 16.9 KB
    const int t = threadIdx.x;
    const int txg = t & 15;       // col group
    const int tyg = t >> 4;       // row group
    const int brow = blockIdx.x * BR;

    // staging mappings
    const int arow = t >> 1;            // 0..127
    const int ah   = (t & 1) * 16;      // d sub-offset
    const int bd   = t >> 3;            // 0..31
    const int bcg  = (t & 7) * 16;      // col sub-offset

    float rrn[8];
    #pragma unroll
    for (int i = 0; i < 8; ++i) {
        int row = (i < 4) ? (4 * tyg + i) : (64 + 4 * tyg + (i - 4));
        rrn[i] = 1.0f / znrm[brow + row];
    }

    float rbV[8]; int rbC[8];
    #pragma unroll
    for (int i = 0; i < 8; ++i) { rbV[i] = -3.4e38f; rbC[i] = 0x7FFFFFFF; }

    for (int cc = 0; cc < NCH; ++cc) {
        const int c0 = cc * CT;
        float acc[8][8];
        #pragma unroll
        for (int i = 0; i < 8; ++i)
            #pragma unroll
            for (int j = 0; j < 8; ++j) acc[i][j] = 0.f;

        for (int s = 0; s < DIM; s += DS) {
            __syncthreads();
            // stage A slice: 128 rows x 32 d, transposed to As[d][row]
            const float* zp = z + (size_t)(brow + arow) * DIM + s + ah;
            float4 av0 = *(const float4*)(zp + 0);
            float4 av1 = *(const float4*)(zp + 4);
            float4 av2 = *(const float4*)(zp + 8);
            float4 av3 = *(const float4*)(zp + 12);
            // stage B slice: 32 d x 128 cols (en_t already [d][k])
            const float* bp = en_t + (size_t)(s + bd) * KCB + c0 + bcg;
            float4 bv0 = *(const float4*)(bp + 0);
            float4 bv1 = *(const float4*)(bp + 4);
            float4 bv2 = *(const float4*)(bp + 8);
            float4 bv3 = *(const float4*)(bp + 12);
            {
                float tmp[16] = {av0.x, av0.y, av0.z, av0.w, av1.x, av1.y, av1.z, av1.w,
                                 av2.x, av2.y, av2.z, av2.w, av3.x, av3.y, av3.z, av3.w};
                #pragma unroll
                for (int q = 0; q < 16; ++q)
                    As[(ah + q) * LSTR + arow] = tmp[q];
            }
            *(float4*)&Bs[bd * LSTR + bcg + 0]  = bv0;
            *(float4*)&Bs[bd * LSTR + bcg + 4]  = bv1;
            *(float4*)&Bs[bd * LSTR + bcg + 8]  = bv2;
            *(float4*)&Bs[bd * LSTR + bcg + 12] = bv3;
            __syncthreads();

            #pragma unroll 4
            for (int dd = 0; dd < DS; ++dd) {
                const float4 aA = *(const float4*)&As[dd * LSTR + 4 * tyg];
                const float4 aB = *(const float4*)&As[dd * LSTR + 64 + 4 * tyg];
                const float4 bA = *(const float4*)&Bs[dd * LSTR + 4 * txg];
                const float4 bB = *(const float4*)&Bs[dd * LSTR + 64 + 4 * txg];
                float a[8] = {aA.x, aA.y, aA.z, aA.w, aB.x, aB.y, aB.z, aB.w};
                float b[8] = {bA.x, bA.y, bA.z, bA.w, bB.x, bB.y, bB.z, bB.w};
                #pragma unroll
                for (int i = 0; i < 8; ++i)
                    #pragma unroll
                    for (int j = 0; j < 8; ++j)
                        acc[i][j] = fmaf(a[i], b[j], acc[i][j]);
            }
        }

        // per-chunk epilogue: row/col argmax
        __syncthreads();
        float2* csc = (float2*)As;   // [16 tyg][128 col], 16 KB
        #pragma unroll
        for (int j = 0; j < 8; ++j) {
            int colL = (j < 4) ? (4 * txg + j) : (64 + 4 * txg + (j - 4));
            int colG = c0 + colL;
            float bv = -3.4e38f; int br = 0x7FFFFFFF;
            #pragma unroll
            for (int i = 0; i < 8; ++i) {
                float dv = acc[i][j] * rrn[i];
                int rowG = brow + ((i < 4) ? (4 * tyg + i) : (64 + 4 * tyg + (i - 4)));
                if (dv > rbV[i] || (dv == rbV[i] && colG < rbC[i])) { rbV[i] = dv; rbC[i] = colG; }
                if (dv > bv || (dv == bv && rowG < br)) { bv = dv; br = rowG; }
            }
            csc[tyg * CT + colL] = make_float2(bv, __int_as_float(br));
        }
        __syncthreads();
        if (t < CT) {
            float bv = -3.4e38f; int br = 0x7FFFFFFF;
            #pragma unroll
            for (int q = 0; q < 16; ++q) {
                float2 e = csc[q * CT + t];
                float v = e.x; int r = __float_as_int(e.y);
                if (v > bv || (v == bv && r < br)) { bv = v; br = r; }
            }
            u64 packed = ((u64)fkey(bv) << 32) | (u64)(0xFFFFFFFFu - (u32)br);
            atomicMax(colmax + c0 + t, packed);
        }
    }

    // final row-argmax reduce across the 16 col groups
    __syncthreads();
    float2* rsc = (float2*)As;       // [16 txg][128 row], 16 KB
    #pragma unroll
    for (int i = 0; i < 8; ++i) {
        int row = (i < 4) ? (4 * tyg + i) : (64 + 4 * tyg + (i - 4));
        rsc[txg * BR + row] = make_float2(rbV[i], __int_as_float(rbC[i]));
    }
    __syncthreads();
    if (t < BR) {
        float bv = -3.4e38f; int bc = 0x7FFFFFFF;
        #pragma unroll
        for (int q = 0; q < 16; ++q) {
            float2 e = rsc[q * BR + t];
            float v = e.x; int c = __float_as_int(e.y);
            if (v > bv || (v == bv && c < bc)) { bv = v; bc = c; }
        }
        idx_out[brow + t] = bc;
    }
}

// ---- K3: gather z_q, write out0, loss partials, histogram ----
__global__ void k_gather(const float* __restrict__ z, const float* __restrict__ emb,
                         const int* __restrict__ idx, float* __restrict__ zq_out,
                         int* __restrict__ counts, float* __restrict__ partials) {
    __shared__ float red[256];
    int t = threadIdx.x;
    int lane = t & 63, w = t >> 6;
    int base = blockIdx.x * 64;
    float acc = 0.f;
    for (int r = 0; r < 16; ++r) {
        int row = base + w * 16 + r;
        int ix = idx[row];
        float4 e  = *(const float4*)(emb + (size_t)ix * DIM + 4 * lane);
        float4 zv = *(const float4*)(z + (size_t)row * DIM + 4 * lane);
        float4 o;
        o.x = zv.x + (e.x - zv.x); o.y = zv.y + (e.y - zv.y);
        o.z = zv.z + (e.z - zv.z); o.w = zv.w + (e.w - zv.w);
        *(float4*)(zq_out + (size_t)row * DIM + 4 * lane) = o;
        float dx = e.x - zv.x, dy = e.y - zv.y, dz = e.z - zv.z, dw = e.w - zv.w;
        acc += dx * dx + dy * dy + dz * dz + dw * dw;
        if (lane == 0) atomicAdd(counts + ix, 1);
    }
    red[t] = acc;
    __syncthreads();
    #pragma unroll
    for (int o = 128; o > 0; o >>= 1) { if (t < o) red[t] += red[t + o]; __syncthreads(); }
    if (t == 0) partials[blockIdx.x] = red[0];
}

// ---- K4: final loss reduce ----
__global__ void k_loss(const float* __restrict__ partials, float* __restrict__ out_loss) {
    __shared__ float red[256];
    int t = threadIdx.x;
    float a = 0.f;
    for (int i = t; i < 2048; i += 256) a += partials[i];
    red[t] = a;
    __syncthreads();
    #pragma unroll
    for (int o = 128; o > 0; o >>= 1) { if (t < o) red[t] += red[t + o]; __syncthreads(); }
    if (t == 0) out_loss[0] = 1.25f * (red[0] / 33554432.0f);
}

// ---- K5: finalize new_embedding + new_embed_prob ----
__global__ void k_final(const float* __restrict__ z, const float* __restrict__ emb,
                        const float* __restrict__ eprob, const int* __restrict__ counts,
                        const u64* __restrict__ colmax,
                        float* __restrict__ out_emb, float* __restrict__ out_prob) {
    int k = blockIdx.x, lane = threadIdx.x;   // 2048 x 64
    u64 p = colmax[k];
    int r = (int)(0xFFFFFFFFu - (u32)(p & 0xFFFFFFFFull));
    float avg = (float)counts[k] * (1.0f / (float)NROWS);
    float nep = eprob[k] * 0.99f + avg * 0.01f;
    float reinit = expf(-(((nep * 2048.0f) * 10.0f) / 0.01f) - 0.001f);
    float4 ev = *(const float4*)(emb + (size_t)k * DIM + 4 * lane);
    float4 zv = *(const float4*)(z + (size_t)r * DIM + 4 * lane);
    float4 o;
    o.x = ev.x * (1.f - reinit) + zv.x * reinit;
    o.y = ev.y * (1.f - reinit) + zv.y * reinit;
    o.z = ev.z * (1.f - reinit) + zv.z * reinit;
    o.w = ev.w * (1.f - reinit) + zv.w * reinit;
    *(float4*)(out_emb + (size_t)k * DIM + 4 * lane) = o;
    if (lane == 0) out_prob[k] = nep;
}

extern "C" void kernel_launch(void* const* d_in, const int* in_sizes, int n_in,
                              void* d_out, int out_size, void* d_ws, size_t ws_size,
                              hipStream_t stream) {
    const float* z   = (const float*)d_in[0];
    const float* emb = (const float*)d_in[1];
    const float* epr = (const float*)d_in[2];

    float* out      = (float*)d_out;
    float* out_zq   = out;                                // NROWS*DIM
    float* out_loss = out + (size_t)NROWS * DIM;          // 1
    float* out_emb  = out_loss + 1;                       // KCB*DIM
    float* out_prob = out_emb + (size_t)KCB * DIM;        // KCB

    char* ws = (char*)d_ws;
    float* en_t   = (float*)(ws + 0);          // 2 MB
    float* znrm   = (float*)(ws + 2097152);    // 512 KB
    int*   idx    = (int*)  (ws + 2621440);    // 512 KB
    u64*   colmax = (u64*)  (ws + 3145728);    // 16 KB
    int*   counts = (int*)  (ws + 3162112);    // 8 KB
    float* parts  = (float*)(ws + 3170304);    // 8 KB

    hipMemsetAsync(colmax, 0, 16384 + 8192, stream);

    k_prep_embed<<<KCB, 64, 0, stream>>>(emb, en_t);
    k_znorm<<<512, 256, 0, stream>>>(z, znrm);
    k_main<<<NROWS / BR, 256, 0, stream>>>(z, en_t, znrm, idx, colmax);
    k_gather<<<NROWS / 64, 256, 0, stream>>>(z, emb, idx, out_zq, counts, parts);
    k_loss<<<1, 256, 0, stream>>>(parts, out_loss);
    k_final<<<KCB, 64, 0, stream>>>(z, emb, epr, counts, colmax, out_emb, out_prob);
}

// Round 3
// 1089.414 us; speedup vs baseline: 1.9790x; 1.6743x over previous
//
#include <hip/hip_runtime.h>

#define NROWS 131072
#define KCB   2048
#define DIM   256
#define BK    32
#define NSTEP 24   // 768 virtual K / 32

typedef unsigned int u32;
typedef unsigned long long u64;
typedef unsigned short u16;
typedef __attribute__((ext_vector_type(8))) short short8;
typedef __attribute__((ext_vector_type(16))) float f32x16;

__device__ __forceinline__ u32 fkey(float f) {
    u32 b = __float_as_uint(f);
    return (b & 0x80000000u) ? ~b : (b | 0x80000000u);
}
__device__ __forceinline__ u16 bf_rne(float x) {
    u32 u = __float_as_uint(x);
    return (u16)((u + 0x7FFFu + ((u >> 16) & 1u)) >> 16);
}
__device__ __forceinline__ void gload16(const u16* src, u16* dst) {
    __builtin_amdgcn_global_load_lds(
        (const __attribute__((address_space(1))) void*)src,
        (__attribute__((address_space(3))) void*)dst, 16, 0, 0);
}

// ---- split a normalized fp32 row into bf16 hi/lo ----
__device__ __forceinline__ void split4(const float4 v, float inv, ushort4& h, ushort4& l) {
    float e[4] = {v.x * inv, v.y * inv, v.z * inv, v.w * inv};
    u16 hh[4]; u16 ll[4];
    #pragma unroll
    for (int q = 0; q < 4; ++q) {
        hh[q] = bf_rne(e[q]);
        float hf = __uint_as_float(((u32)hh[q]) << 16);
        ll[q] = bf_rne(e[q] - hf);
    }
    h = make_ushort4(hh[0], hh[1], hh[2], hh[3]);
    l = make_ushort4(ll[0], ll[1], ll[2], ll[3]);
}

// ---- K0: normalize z rows -> z_hi/z_lo bf16 ----
__global__ void k_prep_z(const float* __restrict__ z, u16* __restrict__ zhi, u16* __restrict__ zlo) {
    int w = threadIdx.x >> 6, lane = threadIdx.x & 63;
    int row = blockIdx.x * 4 + w;
    float4 v = *(const float4*)(z + (size_t)row * DIM + 4 * lane);
    float ss = v.x * v.x + v.y * v.y + v.z * v.z + v.w * v.w;
    #pragma unroll
    for (int o = 32; o > 0; o >>= 1) ss += __shfl_down(ss, o, 64);
    ss = __shfl(ss, 0, 64);
    float inv = 1.0f / fmaxf(sqrtf(ss), 1e-12f);
    ushort4 h, l;
    split4(v, inv, h, l);
    *(ushort4*)(zhi + (size_t)row * DIM + 4 * lane) = h;
    *(ushort4*)(zlo + (size_t)row * DIM + 4 * lane) = l;
}

// ---- K0b: normalize embedding rows -> e_hi/e_lo bf16 ----
__global__ void k_prep_e(const float* __restrict__ emb, u16* __restrict__ ehi, u16* __restrict__ elo) {
    int w = threadIdx.x >> 6, lane = threadIdx.x & 63;
    int row = blockIdx.x * 4 + w;
    float4 v = *(const float4*)(emb + (size_t)row * DIM + 4 * lane);
    float ss = v.x * v.x + v.y * v.y + v.z * v.z + v.w * v.w;
    #pragma unroll
    for (int o = 32; o > 0; o >>= 1) ss += __shfl_down(ss, o, 64);
    ss = __shfl(ss, 0, 64);
    float inv = 1.0f / fmaxf(sqrtf(ss), 1e-12f);
    ushort4 h, l;
    split4(v, inv, h, l);
    *(ushort4*)(ehi + (size_t)row * DIM + 4 * lane) = h;
    *(ushort4*)(elo + (size_t)row * DIM + 4 * lane) = l;
}

// ---- K2: MFMA GEMM (3-pass bf16 split) + row/col argmax ----
// block: 512 thr = 8 waves (2 row-waves x 4 col-waves); tile 256 rows x 256 cols
// wave-tile: 128 rows x 64 cols = 4x2 frags of 32x32; K-step 32 (2 MFMA k-slices)
__launch_bounds__(512, 2)
__global__ void k_mfma(const u16* __restrict__ zhi, const u16* __restrict__ zlo,
                       const u16* __restrict__ ehi, const u16* __restrict__ elo,
                       u64* __restrict__ rowmax, u64* __restrict__ colmax) {
    // per buffer: A = 256 rows x 32k u16 (16KB) at [0], B = 256 cols x 32k (16KB) at [8192]
    __shared__ __align__(16) u16 lds[2][16384];
    const int t = threadIdx.x;
    const int lane = t & 63, l31 = lane & 31, lhi = lane >> 5;
    const int w = t >> 6, wr = w >> 2, wc = w & 3;
    const int brow = (blockIdx.x >> 3) * 256;
    const int bcol = (blockIdx.x & 7) * 256;

    f32x16 acc[4][2];
    #pragma unroll
    for (int i = 0; i < 4; ++i)
        #pragma unroll
        for (int j = 0; j < 2; ++j)
            #pragma unroll
            for (int r = 0; r < 16; ++r) acc[i][j][r] = 0.f;

    auto stage = [&](int b, int u) {
        const int p = u >> 3;
        const int k0 = (u & 7) * BK;
        const u16* ap = (p == 1) ? zlo : zhi;
        const u16* bp = (p == 2) ? elo : ehi;
        #pragma unroll
        for (int q = 0; q < 2; ++q) {
            int f = q * 512 + t;
            int r = f >> 2, seg = (f & 3) ^ (r & 3);
            gload16(ap + (size_t)(brow + r) * DIM + k0 + seg * 8, &lds[b][(size_t)f * 8]);
        }
        #pragma unroll
        for (int q = 0; q < 2; ++q) {
            int f = q * 512 + t;
            int r = f >> 2, seg = (f & 3) ^ (r & 3);
            gload16(bp + (size_t)(bcol + r) * DIM + k0 + seg * 8, &lds[b][8192 + (size_t)f * 8]);
        }
    };

    auto comp = [&](int b) {
        short8 af[4][2], bfr[2][2];
        #pragma unroll
        for (int i = 0; i < 4; ++i)
            #pragma unroll
            for (int s = 0; s < 2; ++s) {
                int r = wr * 128 + i * 32 + l31;
                int seg = (s * 2 + lhi) ^ (r & 3);
                af[i][s] = *(const short8*)&lds[b][(size_t)r * 32 + seg * 8];
            }
        #pragma unroll
        for (int j = 0; j < 2; ++j)
            #pragma unroll
            for (int s = 0; s < 2; ++s) {
                int c = wc * 64 + j * 32 + l31;
                int seg = (s * 2 + lhi) ^ (c & 3);
                bfr[j][s] = *(const short8*)&lds[b][8192 + (size_t)c * 32 + seg * 8];
            }
        #pragma unroll
        for (int s = 0; s < 2; ++s)
            #pragma unroll
            for (int i = 0; i < 4; ++i)
                #pragma unroll
                for (int j = 0; j < 2; ++j)
                    acc[i][j] = __builtin_amdgcn_mfma_f32_32x32x16_bf16(af[i][s], bfr[j][s], acc[i][j], 0, 0, 0);
    };

    stage(0, 0);
    __syncthreads();
    for (int u = 0; u < NSTEP; ++u) {
        if (u + 1 < NSTEP) stage((u + 1) & 1, u + 1);
        comp(u & 1);
        __syncthreads();
    }

    // ---- epilogue: argmax reductions (LDS buffers now free) ----
    float2* colred = (float2*)&lds[0][0];      // [2 wr][256 cols]  (4 KB)
    float2* rowred = (float2*)&lds[0][2048];   // [4 wc][256 rows]  (8 KB)

    // col argmax: per wave over its 128 rows
    #pragma unroll
    for (int j = 0; j < 2; ++j) {
        float bv = -3.4e38f; int brw = 0x7FFFFFFF;
        #pragma unroll
        for (int i = 0; i < 4; ++i)
            #pragma unroll
            for (int r = 0; r < 16; ++r) {
                float v = acc[i][j][r];
                int rg = brow + wr * 128 + i * 32 + (r & 3) + 8 * (r >> 2) + 4 * lhi;
                if (v > bv || (v == bv && rg < brw)) { bv = v; brw = rg; }
            }
        float ov = __shfl_xor(bv, 32); int orw = __shfl_xor(brw, 32);
        if (ov > bv || (ov == bv && orw < brw)) { bv = ov; brw = orw; }
        if (lane < 32) colred[wr * 256 + wc * 64 + j * 32 + l31] = make_float2(bv, __int_as_float(brw));
    }

    // row argmax: butterfly across 32 col-lanes
    #pragma unroll
    for (int i = 0; i < 4; ++i) {
        #pragma unroll
        for (int r = 0; r < 16; ++r) {
            float v0 = acc[i][0][r], v1 = acc[i][1][r];
            int c0 = bcol + wc * 64 + l31;
            float bv; int bc;
            if (v1 > v0) { bv = v1; bc = c0 + 32; } else { bv = v0; bc = c0; }
            #pragma unroll
            for (int m = 16; m >= 1; m >>= 1) {
                float ov = __shfl_xor(bv, m);
                int oc = __shfl_xor(bc, m);
                if (ov > bv || (ov == bv && oc < bc)) { bv = ov; bc = oc; }
            }
            if (l31 == 0) {
                int rloc = wr * 128 + i * 32 + (r & 3) + 8 * (r >> 2) + 4 * lhi;
                rowred[wc * 256 + rloc] = make_float2(bv, __int_as_float(bc));
            }
        }
    }
    __syncthreads();

    if (t < 256) {
        // combine col partials across 2 row-waves
        float2 e0 = colred[t], e1 = colred[256 + t];
        float bv = e0.x; int brw = __float_as_int(e0.y);
        if (e1.x > bv || (e1.x == bv && __float_as_int(e1.y) < brw)) { bv = e1.x; brw = __float_as_int(e1.y); }
        atomicMax(colmax + bcol + t, ((u64)fkey(bv) << 32) | (u64)(~(u32)brw));
    }
    if (t < 256) {
        // combine row partials across 4 col-waves
        float bv = -3.4e38f; int bc = 0x7FFFFFFF;
        #pragma unroll
        for (int q = 0; q < 4; ++q) {
            float2 e = rowred[q * 256 + t];
            if (e.x > bv || (e.x == bv && __float_as_int(e.y) < bc)) { bv = e.x; bc = __float_as_int(e.y); }
        }
        atomicMax(rowmax + brow + t, ((u64)fkey(bv) << 32) | (u64)(~(u32)bc));
    }
}

// ---- K3: gather z_q, write out0, loss partials, histogram ----
__global__ void k_gather(const float* __restrict__ z, const float* __restrict__ emb,
                         const u64* __restrict__ rowmax, float* __restrict__ zq_out,
                         int* __restrict__ counts, float* __restrict__ partials) {
    __shared__ float red[256];
    int t = threadIdx.x;
    int lane = t & 63, w = t >> 6;
    int base = blockIdx.x * 64;
    float acc = 0.f;
    for (int r = 0; r < 16; ++r) {
        int row = base + w * 16 + r;
        int ix = (int)(~(u32)(rowmax[row] & 0xFFFFFFFFull));
        float4 e  = *(const float4*)(emb + (size_t)ix * DIM + 4 * lane);
        float4 zv = *(const float4*)(z + (size_t)row * DIM + 4 * lane);
        float4 o;
        o.x = zv.x + (e.x - zv.x); o.y = zv.y + (e.y - zv.y);
        o.z = zv.z + (e.z - zv.z); o.w = zv.w + (e.w - zv.w);
        *(float4*)(zq_out + (size_t)row * DIM + 4 * lane) = o;
        float dx = e.x - zv.x, dy = e.y - zv.y, dz = e.z - zv.z, dw = e.w - zv.w;
        acc += dx * dx + dy * dy + dz * dz + dw * dw;
        if (lane == 0) atomicAdd(counts + ix, 1);
    }
    red[t] = acc;
    __syncthreads();
    #pragma unroll
    for (int o = 128; o > 0; o >>= 1) { if (t < o) red[t] += red[t + o]; __syncthreads(); }
    if (t == 0) partials[blockIdx.x] = red[0];
}

// ---- K4: final loss reduce ----
__global__ void k_loss(const float* __restrict__ partials, float* __restrict__ out_loss) {
    __shared__ float red[256];
    int t = threadIdx.x;
    float a = 0.f;
    for (int i = t; i < 2048; i += 256) a += partials[i];
    red[t] = a;
    __syncthreads();
    #pragma unroll
    for (int o = 128; o > 0; o >>= 1) { if (t < o) red[t] += red[t + o]; __syncthreads(); }
    if (t == 0) out_loss[0] = 1.25f * (red[0] / 33554432.0f);
}

// ---- K5: finalize new_embedding + new_embed_prob ----
__global__ void k_final(const float* __restrict__ z, const float* __restrict__ emb,
                        const float* __restrict__ eprob, const int* __restrict__ counts,
                        const u64* __restrict__ colmax,
                        float* __restrict__ out_emb, float* __restrict__ out_prob) {
    int k = blockIdx.x, lane = threadIdx.x;   // 2048 x 64
    int r = (int)(~(u32)(colmax[k] & 0xFFFFFFFFull));
    float avg = (float)counts[k] * (1.0f / (float)NROWS);
    float nep = eprob[k] * 0.99f + avg * 0.01f;
    float reinit = expf(-(((nep * 2048.0f) * 10.0f) / 0.01f) - 0.001f);
    float4 ev = *(const float4*)(emb + (size_t)k * DIM + 4 * lane);
    float4 zv = *(const float4*)(z + (size_t)r * DIM + 4 * lane);
    float4 o;
    o.x = ev.x * (1.f - reinit) + zv.x * reinit;
    o.y = ev.y * (1.f - reinit) + zv.y * reinit;
    o.z = ev.z * (1.f - reinit) + zv.z * reinit;
    o.w = ev.w * (1.f - reinit) + zv.w * reinit;
    *(float4*)(out_emb + (size_t)k * DIM + 4 * lane) = o;
    if (lane == 0) out_prob[k] = nep;
}

extern "C" void kernel_launch(void* const* d_in, const int* in_sizes, int n_in,
                              void* d_out, int out_size, void* d_ws, size_t ws_size,
                              hipStream_t stream) {
    const float* z   = (const float*)d_in[0];
    const float* emb = (const float*)d_in[1];
    const float* epr = (const float*)d_in[2];

    float* out      = (float*)d_out;
    float* out_zq   = out;                                // NROWS*DIM floats
    float* out_loss = out + (size_t)NROWS * DIM;          // 1
    float* out_emb  = out_loss + 1;                       // KCB*DIM
    float* out_prob = out_emb + (size_t)KCB * DIM;        // KCB

    // z_hi/z_lo live in the zq region of d_out (exactly 134,217,728 bytes);
    // k_gather overwrites it after k_mfma has consumed it.
    u16* zhi = (u16*)d_out;
    u16* zlo = zhi + (size_t)NROWS * DIM;

    char* ws = (char*)d_ws;
    u16*   ehi    = (u16*)  (ws + 0);          // 1 MB
    u16*   elo    = (u16*)  (ws + 1048576);    // 1 MB
    u64*   rowmax = (u64*)  (ws + 2097152);    // 1 MB
    u64*   colmax = (u64*)  (ws + 3145728);    // 16 KB
    int*   counts = (int*)  (ws + 3162112);    // 8 KB
    float* parts  = (float*)(ws + 3170304);    // 8 KB

    // zero rowmax + colmax + counts (contiguous)
    hipMemsetAsync(rowmax, 0, 1048576 + 16384 + 8192, stream);

    k_prep_z<<<NROWS / 4, 256, 0, stream>>>(z, zhi, zlo);
    k_prep_e<<<KCB / 4, 256, 0, stream>>>(emb, ehi, elo);
    k_mfma<<<(NROWS / 256) * 8, 512, 0, stream>>>(zhi, zlo, ehi, elo, rowmax, colmax);
    k_gather<<<NROWS / 64, 256, 0, stream>>>(z, emb, rowmax, out_zq, counts, parts);
    k_loss<<<1, 256, 0, stream>>>(parts, out_loss);
    k_final<<<KCB, 64, 0, stream>>>(z, emb, epr, counts, colmax, out_emb, out_prob);
}

// Round 4
// 1054.993 us; speedup vs baseline: 2.0436x; 1.0326x over previous
//
#include <hip/hip_runtime.h>

#define NROWS 131072
#define KCB   2048
#define DIM   256
#define NT    12    // virtual-K tiles: 768 / 64

typedef unsigned int u32;
typedef unsigned long long u64;
typedef unsigned short u16;
typedef __attribute__((ext_vector_type(8))) short short8;
typedef __attribute__((ext_vector_type(16))) float f32x16;

__device__ __forceinline__ u32 fkey(float f) {
    u32 b = __float_as_uint(f);
    return (b & 0x80000000u) ? ~b : (b | 0x80000000u);
}
__device__ __forceinline__ u16 bf_rne(float x) {
    u32 u = __float_as_uint(x);
    return (u16)((u + 0x7FFFu + ((u >> 16) & 1u)) >> 16);
}
__device__ __forceinline__ void gload16(const u16* src, u16* dst) {
    __builtin_amdgcn_global_load_lds(
        (const __attribute__((address_space(1))) void*)src,
        (__attribute__((address_space(3))) void*)dst, 16, 0, 0);
}

__device__ __forceinline__ void split4(const float4 v, float inv, ushort4& h, ushort4& l) {
    float e[4] = {v.x * inv, v.y * inv, v.z * inv, v.w * inv};
    u16 hh[4]; u16 ll[4];
    #pragma unroll
    for (int q = 0; q < 4; ++q) {
        hh[q] = bf_rne(e[q]);
        float hf = __uint_as_float(((u32)hh[q]) << 16);
        ll[q] = bf_rne(e[q] - hf);
    }
    h = make_ushort4(hh[0], hh[1], hh[2], hh[3]);
    l = make_ushort4(ll[0], ll[1], ll[2], ll[3]);
}

// ---- K0: normalize z rows -> z_hi/z_lo bf16 ----
__global__ void k_prep_z(const float* __restrict__ z, u16* __restrict__ zhi, u16* __restrict__ zlo) {
    int w = threadIdx.x >> 6, lane = threadIdx.x & 63;
    int row = blockIdx.x * 4 + w;
    float4 v = *(const float4*)(z + (size_t)row * DIM + 4 * lane);
    float ss = v.x * v.x + v.y * v.y + v.z * v.z + v.w * v.w;
    #pragma unroll
    for (int o = 32; o > 0; o >>= 1) ss += __shfl_down(ss, o, 64);
    ss = __shfl(ss, 0, 64);
    float inv = 1.0f / fmaxf(sqrtf(ss), 1e-12f);
    ushort4 h, l;
    split4(v, inv, h, l);
    *(ushort4*)(zhi + (size_t)row * DIM + 4 * lane) = h;
    *(ushort4*)(zlo + (size_t)row * DIM + 4 * lane) = l;
}

// ---- K0b: normalize embedding rows -> e_hi/e_lo bf16 ----
__global__ void k_prep_e(const float* __restrict__ emb, u16* __restrict__ ehi, u16* __restrict__ elo) {
    int w = threadIdx.x >> 6, lane = threadIdx.x & 63;
    int row = blockIdx.x * 4 + w;
    float4 v = *(const float4*)(emb + (size_t)row * DIM + 4 * lane);
    float ss = v.x * v.x + v.y * v.y + v.z * v.z + v.w * v.w;
    #pragma unroll
    for (int o = 32; o > 0; o >>= 1) ss += __shfl_down(ss, o, 64);
    ss = __shfl(ss, 0, 64);
    float inv = 1.0f / fmaxf(sqrtf(ss), 1e-12f);
    ushort4 h, l;
    split4(v, inv, h, l);
    *(ushort4*)(ehi + (size_t)row * DIM + 4 * lane) = h;
    *(ushort4*)(elo + (size_t)row * DIM + 4 * lane) = l;
}

// ---- K2: MFMA GEMM, 256x256 tile, BK=64, phased schedule w/ counted vmcnt ----
// 8 waves (2 row x 4 col), wave-tile 128x64 = 4x2 frags of 32x32x16.
// LDS per buffer: A = 256 rows x 128B (32KB), B = 256 cols x 128B (32KB); x2 dbuf = 128KB.
// Swizzle: 16B-segment ps = gs ^ (row&7) -> ds_read_b128 covers all 32 banks.
__launch_bounds__(512, 1)
__global__ void k_mfma(const u16* __restrict__ zhi, const u16* __restrict__ zlo,
                       const u16* __restrict__ ehi, const u16* __restrict__ elo,
                       u64* __restrict__ rowmax, u64* __restrict__ colmax) {
    __shared__ __align__(16) u16 lds[2][32768];   // [buf][A:0..16383 | B:16384..32767]
    const int t = threadIdx.x;
    const int lane = t & 63, l31 = lane & 31, lhi = lane >> 5;
    const int w = t >> 6, wr = w >> 2, wc = w & 3;

    // T1: bijective XCD swizzle (nwg=4096, 8 XCDs, 512 per XCD): the 8 col-tiles
    // of a row-panel run consecutively on ONE XCD -> A-panel L2 reuse.
    const int swz = (blockIdx.x & 7) * 512 + (blockIdx.x >> 3);
    const int brow = (swz >> 3) * 256;
    const int bcol = (swz & 7) * 256;

    f32x16 acc[4][2];
    #pragma unroll
    for (int i = 0; i < 4; ++i)
        #pragma unroll
        for (int j = 0; j < 2; ++j)
            #pragma unroll
            for (int r = 0; r < 16; ++r) acc[i][j][r] = 0.f;

    auto stage = [&](int b, int u) {
        const int p = u >> 2;
        const int k0 = (u & 3) * 64;
        const u16* ap = (p == 1) ? zlo : zhi;
        const u16* bp = (p == 2) ? elo : ehi;
        #pragma unroll
        for (int q = 0; q < 4; ++q) {
            int f = q * 512 + t;                 // 16B chunk id, 0..2047
            int r = f >> 3, ps = f & 7, gs = ps ^ (r & 7);
            gload16(ap + (size_t)(brow + r) * DIM + k0 + gs * 8, &lds[b][f * 8]);
        }
        #pragma unroll
        for (int q = 0; q < 4; ++q) {
            int f = q * 512 + t;
            int r = f >> 3, ps = f & 7, gs = ps ^ (r & 7);
            gload16(bp + (size_t)(bcol + r) * DIM + k0 + gs * 8, &lds[b][16384 + f * 8]);
        }
    };

    auto phase = [&](int b, int ks) {            // one 16-k slice of the BK=64 tile
        short8 af[4], bf2[2];
        #pragma unroll
        for (int i = 0; i < 4; ++i) {
            int r = wr * 128 + i * 32 + l31;
            int seg = (ks * 2 + lhi) ^ (r & 7);
            af[i] = *(const short8*)&lds[b][r * 64 + seg * 8];
        }
        #pragma unroll
        for (int j = 0; j < 2; ++j) {
            int c = wc * 64 + j * 32 + l31;
            int seg = (ks * 2 + lhi) ^ (c & 7);
            bf2[j] = *(const short8*)&lds[b][16384 + c * 64 + seg * 8];
        }
        __builtin_amdgcn_s_barrier();
        asm volatile("s_waitcnt lgkmcnt(0)");
        __builtin_amdgcn_sched_barrier(0);
        __builtin_amdgcn_s_setprio(1);
        #pragma unroll
        for (int i = 0; i < 4; ++i)
            #pragma unroll
            for (int j = 0; j < 2; ++j)
                acc[i][j] = __builtin_amdgcn_mfma_f32_32x32x16_bf16(af[i], bf2[j], acc[i][j], 0, 0, 0);
        __builtin_amdgcn_s_setprio(0);
        __builtin_amdgcn_s_barrier();
    };

    // prologue: 2-deep prefetch
    stage(0, 0);
    stage(1, 1);
    asm volatile("s_waitcnt vmcnt(8)" ::: "memory");   // tile 0 landed (tile 1 in flight)
    __builtin_amdgcn_s_barrier();

    for (int u = 0; u < NT; ++u) {
        const int b = u & 1;
        #pragma unroll
        for (int ks = 0; ks < 4; ++ks) phase(b, ks);
        // buf b fully consumed by all waves (last phase barrier) -> refill for u+2
        if (u + 2 < NT) {
            stage(b, u + 2);
            asm volatile("s_waitcnt vmcnt(8)" ::: "memory");   // tile u+1 landed
        } else if (u + 1 < NT) {
            asm volatile("s_waitcnt vmcnt(0)" ::: "memory");   // final tile landed
        }
        __builtin_amdgcn_s_barrier();
    }

    // ---- epilogue: argmax reductions (LDS now free) ----
    float2* colred = (float2*)&lds[0][0];      // [2 wr][256 cols]  (4 KB)
    float2* rowred = (float2*)&lds[0][2048];   // [4 wc][256 rows]  (8 KB)

    #pragma unroll
    for (int j = 0; j < 2; ++j) {
        float bv = -3.4e38f; int brw = 0x7FFFFFFF;
        #pragma unroll
        for (int i = 0; i < 4; ++i)
            #pragma unroll
            for (int r = 0; r < 16; ++r) {
                float v = acc[i][j][r];
                int rg = brow + wr * 128 + i * 32 + (r & 3) + 8 * (r >> 2) + 4 * lhi;
                if (v > bv || (v == bv && rg < brw)) { bv = v; brw = rg; }
            }
        float ov = __shfl_xor(bv, 32); int orw = __shfl_xor(brw, 32);
        if (ov > bv || (ov == bv && orw < brw)) { bv = ov; brw = orw; }
        if (lane < 32) colred[wr * 256 + wc * 64 + j * 32 + l31] = make_float2(bv, __int_as_float(brw));
    }

    #pragma unroll
    for (int i = 0; i < 4; ++i) {
        #pragma unroll
        for (int r = 0; r < 16; ++r) {
            float v0 = acc[i][0][r], v1 = acc[i][1][r];
            int c0 = bcol + wc * 64 + l31;
            float bv; int bc;
            if (v1 > v0) { bv = v1; bc = c0 + 32; } else { bv = v0; bc = c0; }
            #pragma unroll
            for (int m = 16; m >= 1; m >>= 1) {
                float ov = __shfl_xor(bv, m);
                int oc = __shfl_xor(bc, m);
                if (ov > bv || (ov == bv && oc < bc)) { bv = ov; bc = oc; }
            }
            if (l31 == 0) {
                int rloc = wr * 128 + i * 32 + (r & 3) + 8 * (r >> 2) + 4 * lhi;
                rowred[wc * 256 + rloc] = make_float2(bv, __int_as_float(bc));
            }
        }
    }
    __syncthreads();

    if (t < 256) {
        float2 e0 = colred[t], e1 = colred[256 + t];
        float bv = e0.x; int brw = __float_as_int(e0.y);
        if (e1.x > bv || (e1.x == bv && __float_as_int(e1.y) < brw)) { bv = e1.x; brw = __float_as_int(e1.y); }
        atomicMax(colmax + bcol + t, ((u64)fkey(bv) << 32) | (u64)(~(u32)brw));
    }
    if (t < 256) {
        float bv = -3.4e38f; int bc = 0x7FFFFFFF;
        #pragma unroll
        for (int q = 0; q < 4; ++q) {
            float2 e = rowred[q * 256 + t];
            if (e.x > bv || (e.x == bv && __float_as_int(e.y) < bc)) { bv = e.x; bc = __float_as_int(e.y); }
        }
        atomicMax(rowmax + brow + t, ((u64)fkey(bv) << 32) | (u64)(~(u32)bc));
    }
}

// ---- K3: gather z_q, write out0, loss partials, histogram ----
__global__ void k_gather(const float* __restrict__ z, const float* __restrict__ emb,
                         const u64* __restrict__ rowmax, float* __restrict__ zq_out,
                         int* __restrict__ counts, float* __restrict__ partials) {
    __shared__ float red[256];
    int t = threadIdx.x;
    int lane = t & 63, w = t >> 6;
    int base = blockIdx.x * 64;
    float acc = 0.f;
    for (int r = 0; r < 16; ++r) {
        int row = base + w * 16 + r;
        int ix = (int)(~(u32)(rowmax[row] & 0xFFFFFFFFull));
        float4 e  = *(const float4*)(emb + (size_t)ix * DIM + 4 * lane);
        float4 zv = *(const float4*)(z + (size_t)row * DIM + 4 * lane);
        float4 o;
        o.x = zv.x + (e.x - zv.x); o.y = zv.y + (e.y - zv.y);
        o.z = zv.z + (e.z - zv.z); o.w = zv.w + (e.w - zv.w);
        *(float4*)(zq_out + (size_t)row * DIM + 4 * lane) = o;
        float dx = e.x - zv.x, dy = e.y - zv.y, dz = e.z - zv.z, dw = e.w - zv.w;
        acc += dx * dx + dy * dy + dz * dz + dw * dw;
        if (lane == 0) atomicAdd(counts + ix, 1);
    }
    red[t] = acc;
    __syncthreads();
    #pragma unroll
    for (int o = 128; o > 0; o >>= 1) { if (t < o) red[t] += red[t + o]; __syncthreads(); }
    if (t == 0) partials[blockIdx.x] = red[0];
}

// ---- K4: final loss reduce ----
__global__ void k_loss(const float* __restrict__ partials, float* __restrict__ out_loss) {
    __shared__ float red[256];
    int t = threadIdx.x;
    float a = 0.f;
    for (int i = t; i < 2048; i += 256) a += partials[i];
    red[t] = a;
    __syncthreads();
    #pragma unroll
    for (int o = 128; o > 0; o >>= 1) { if (t < o) red[t] += red[t + o]; __syncthreads(); }
    if (t == 0) out_loss[0] = 1.25f * (red[0] / 33554432.0f);
}

// ---- K5: finalize new_embedding + new_embed_prob ----
__global__ void k_final(const float* __restrict__ z, const float* __restrict__ emb,
                        const float* __restrict__ eprob, const int* __restrict__ counts,
                        const u64* __restrict__ colmax,
                        float* __restrict__ out_emb, float* __restrict__ out_prob) {
    int k = blockIdx.x, lane = threadIdx.x;   // 2048 x 64
    int r = (int)(~(u32)(colmax[k] & 0xFFFFFFFFull));
    float avg = (float)counts[k] * (1.0f / (float)NROWS);
    float nep = eprob[k] * 0.99f + avg * 0.01f;
    float reinit = expf(-(((nep * 2048.0f) * 10.0f) / 0.01f) - 0.001f);
    float4 ev = *(const float4*)(emb + (size_t)k * DIM + 4 * lane);
    float4 zv = *(const float4*)(z + (size_t)r * DIM + 4 * lane);
    float4 o;
    o.x = ev.x * (1.f - reinit) + zv.x * reinit;
    o.y = ev.y * (1.f - reinit) + zv.y * reinit;
    o.z = ev.z * (1.f - reinit) + zv.z * reinit;
    o.w = ev.w * (1.f - reinit) + zv.w * reinit;
    *(float4*)(out_emb + (size_t)k * DIM + 4 * lane) = o;
    if (lane == 0) out_prob[k] = nep;
}

extern "C" void kernel_launch(void* const* d_in, const int* in_sizes, int n_in,
                              void* d_out, int out_size, void* d_ws, size_t ws_size,
                              hipStream_t stream) {
    const float* z   = (const float*)d_in[0];
    const float* emb = (const float*)d_in[1];
    const float* epr = (const float*)d_in[2];

    float* out      = (float*)d_out;
    float* out_zq   = out;                                // NROWS*DIM floats
    float* out_loss = out + (size_t)NROWS * DIM;          // 1
    float* out_emb  = out_loss + 1;                       // KCB*DIM
    float* out_prob = out_emb + (size_t)KCB * DIM;        // KCB

    // z_hi/z_lo live in the zq region of d_out (exactly 134,217,728 bytes);
    // k_gather overwrites it after k_mfma has consumed it.
    u16* zhi = (u16*)d_out;
    u16* zlo = zhi + (size_t)NROWS * DIM;

    char* ws = (char*)d_ws;
    u16*   ehi    = (u16*)  (ws + 0);          // 1 MB
    u16*   elo    = (u16*)  (ws + 1048576);    // 1 MB
    u64*   rowmax = (u64*)  (ws + 2097152);    // 1 MB
    u64*   colmax = (u64*)  (ws + 3145728);    // 16 KB
    int*   counts = (int*)  (ws + 3162112);    // 8 KB
    float* parts  = (float*)(ws + 3170304);    // 8 KB

    hipMemsetAsync(rowmax, 0, 1048576 + 16384 + 8192, stream);

    k_prep_z<<<NROWS / 4, 256, 0, stream>>>(z, zhi, zlo);
    k_prep_e<<<KCB / 4, 256, 0, stream>>>(emb, ehi, elo);
    k_mfma<<<(NROWS / 256) * 8, 512, 0, stream>>>(zhi, zlo, ehi, elo, rowmax, colmax);
    k_gather<<<NROWS / 64, 256, 0, stream>>>(z, emb, rowmax, out_zq, counts, parts);
    k_loss<<<1, 256, 0, stream>>>(parts, out_loss);
    k_final<<<KCB, 64, 0, stream>>>(z, emb, epr, counts, colmax, out_emb, out_prob);
}